// Round 2
// baseline (582.072 us; speedup 1.0000x reference)
//
#include <hip/hip_runtime.h>

typedef unsigned short u16;
typedef __bf16 bf16x8 __attribute__((ext_vector_type(8)));
typedef float f32x4 __attribute__((ext_vector_type(4)));

#define NQ 16384       // queries (8*2048)
#define NC 16384       // codes
#define DD 256         // embed dim
#define BM 128
#define BN 128
#define BK 64
#define NSPLIT 8
#define NPART (NSPLIT * 2)            // 16: per-(split, wn) partials (race fix)
#define NTILES ((NC / NSPLIT) / BN)   // 16

// ---------- fp32 -> bf16 hi/lo split (RNE) ----------
__device__ __forceinline__ u16 f2bf(float x) {
  unsigned u = __float_as_uint(x);
  u += 0x7fffu + ((u >> 16) & 1u);
  return (u16)(u >> 16);
}
__device__ __forceinline__ float bf2f(u16 h) {
  return __uint_as_float(((unsigned)h) << 16);
}

// async global->LDS, 16B per lane; LDS dest is wave-uniform base + lane*16
__device__ __forceinline__ void gl2lds16(const void* g, void* l) {
  __builtin_amdgcn_global_load_lds((__attribute__((address_space(1))) void*)g,
                                   (__attribute__((address_space(3))) void*)l,
                                   16, 0, 0);
}

// ---------- K0: split z into bf16 hi/lo ----------
__global__ __launch_bounds__(256) void split_z_kernel(const float* __restrict__ z,
                                                      u16* __restrict__ Ah,
                                                      u16* __restrict__ Al) {
  size_t i = (size_t)blockIdx.x * 256 + threadIdx.x;   // float4 index
  float4 v = ((const float4*)z)[i];
  float f[4] = {v.x, v.y, v.z, v.w};
  u16 hh[4], ll[4];
#pragma unroll
  for (int j = 0; j < 4; ++j) {
    hh[j] = f2bf(f[j]);
    ll[j] = f2bf(f[j] - bf2f(hh[j]));
  }
  ushort4 h; h.x = hh[0]; h.y = hh[1]; h.z = hh[2]; h.w = hh[3];
  ushort4 l; l.x = ll[0]; l.y = ll[1]; l.z = ll[2]; l.w = ll[3];
  ((ushort4*)Ah)[i] = h;
  ((ushort4*)Al)[i] = l;
}

// ---------- K0b: row norms in EXACT numpy pairwise order ----------
// np.sum(x*x, axis=1) for len-256 rows: split into two 128-halves; each half:
// 8 accumulators r[j] = x[j]^2, then r[j] += x[i+j]^2 for i=8..120 step 8,
// combine ((r0+r1)+(r2+r3))+((r4+r5)+(r6+r7)); total = half0 + half1.
// __fmul_rn/__fadd_rn prevent FMA contraction (numpy rounds square then add).
__global__ __launch_bounds__(64) void norm256_kernel(const float* __restrict__ x,
                                                     float* __restrict__ nrm) {
  const int row = blockIdx.x * 64 + threadIdx.x;
  const float* p = x + (size_t)row * 256;
  float half[2];
#pragma unroll
  for (int h = 0; h < 2; ++h) {
    const float* q = p + h * 128;
    float r[8];
#pragma unroll
    for (int j = 0; j < 8; ++j) r[j] = __fmul_rn(q[j], q[j]);
    for (int i = 8; i < 128; i += 8)
#pragma unroll
      for (int j = 0; j < 8; ++j) r[j] = __fadd_rn(r[j], __fmul_rn(q[i + j], q[i + j]));
    half[h] = __fadd_rn(__fadd_rn(__fadd_rn(r[0], r[1]), __fadd_rn(r[2], r[3])),
                        __fadd_rn(__fadd_rn(r[4], r[5]), __fadd_rn(r[6], r[7])));
  }
  nrm[row] = __fadd_rn(half[0], half[1]);
}

// ---------- K1: qc = cb @ W^T + bias  (fp32, 64x64 tiles) ----------
__global__ __launch_bounds__(256) void qc_gemm_kernel(const float* __restrict__ cb,
                                                      const float* __restrict__ W,
                                                      const float* __restrict__ bias,
                                                      float* __restrict__ qc) {
  __shared__ float As[64][33];
  __shared__ float Bs[64][33];
  const int bm = blockIdx.x >> 2;   // 256 row tiles
  const int bn = blockIdx.x & 3;    // 4 col tiles
  const int m0 = bm * 64, n0 = bn * 64;
  const int t = threadIdx.x;
  const int tx = t & 15, ty = t >> 4;
  float acc[4][4] = {};
  for (int kc = 0; kc < 256; kc += 32) {
    __syncthreads();
#pragma unroll
    for (int j = 0; j < 8; ++j) {
      int idx = j * 256 + t;            // 0..2047
      int r = idx >> 5, c = idx & 31;
      As[r][c] = cb[(size_t)(m0 + r) * 256 + kc + c];
      Bs[r][c] = W[(size_t)(n0 + r) * 256 + kc + c];
    }
    __syncthreads();
#pragma unroll
    for (int kk = 0; kk < 32; ++kk) {
      float a[4], b[4];
#pragma unroll
      for (int u = 0; u < 4; ++u) a[u] = As[ty * 4 + u][kk];
#pragma unroll
      for (int v = 0; v < 4; ++v) b[v] = Bs[tx * 4 + v][kk];
#pragma unroll
      for (int u = 0; u < 4; ++u)
#pragma unroll
        for (int v = 0; v < 4; ++v) acc[u][v] += a[u] * b[v];
    }
  }
#pragma unroll
  for (int u = 0; u < 4; ++u)
#pragma unroll
    for (int v = 0; v < 4; ++v) {
      int r = m0 + ty * 4 + u, c = n0 + tx * 4 + v;
      qc[(size_t)r * 256 + c] = acc[u][v] + bias[c];
    }
}

// ---------- K1b: per-row bf16 hi/lo split of qc ----------
__global__ __launch_bounds__(256) void split_qc_kernel(const float* __restrict__ qc,
                                                       u16* __restrict__ Bh,
                                                       u16* __restrict__ Bl) {
  size_t i = (size_t)blockIdx.x * 256 + threadIdx.x;   // float4 index
  float4 v = ((const float4*)qc)[i];
  float f[4] = {v.x, v.y, v.z, v.w};
  u16 hh[4], ll[4];
#pragma unroll
  for (int j = 0; j < 4; ++j) {
    hh[j] = f2bf(f[j]);
    ll[j] = f2bf(f[j] - bf2f(hh[j]));
  }
  ushort4 h; h.x = hh[0]; h.y = hh[1]; h.z = hh[2]; h.w = hh[3];
  ushort4 l; l.x = ll[0]; l.y = ll[1]; l.z = ll[2]; l.w = ll[3];
  ((ushort4*)Bh)[i] = h;
  ((ushort4*)Bl)[i] = l;
}

// ---------- K2: fused split-bf16 distance GEMM + argmin ----------
// dist replicates np op order: fl(fl(zn + cn) - fl(2*dot)) so near-ties land
// on the same ~3e-5 rounding grid as the reference.
__global__ __launch_bounds__(256, 2) void vq_argmin_kernel(
    const u16* __restrict__ Ah, const u16* __restrict__ Al,
    const u16* __restrict__ Bh, const u16* __restrict__ Bl,
    const float* __restrict__ cnorm, const float* __restrict__ znorm,
    float* __restrict__ pval, int* __restrict__ pidx) {
  __shared__ __align__(16) u16 Ahs[BM * BK];
  __shared__ __align__(16) u16 Als[BM * BK];
  __shared__ __align__(16) u16 Bhs[BN * BK];
  __shared__ __align__(16) u16 Bls[BN * BK];

  const int bm = blockIdx.x / NSPLIT;
  const int spl = blockIdx.x % NSPLIT;
  const int lane = threadIdx.x & 63;
  const int wid = threadIdx.x >> 6;
  const int wm = wid >> 1, wn = wid & 1;     // 2x2 wave grid, 64x64 each
  const int l15 = lane & 15;
  const int lg = lane >> 4;                  // 0..3
  const int m0 = bm * BM;
  const int ns0 = spl * (NC / NSPLIT);

  const int st_r = lane >> 3;                // row within 8-row group
  const int st_g = (lane & 7) * 8;           // k elem offset

  // query-row norms for this lane's 16 C/D rows (row = wm*64+mi*16+lg*4+i)
  float zrow[4][4];
#pragma unroll
  for (int mi = 0; mi < 4; ++mi)
#pragma unroll
    for (int i = 0; i < 4; ++i)
      zrow[mi][i] = znorm[m0 + wm * 64 + mi * 16 + lg * 4 + i];

  float rmin[4][4];
  int ridx[4][4];
#pragma unroll
  for (int a = 0; a < 4; ++a)
#pragma unroll
    for (int b = 0; b < 4; ++b) { rmin[a][b] = 3.4e38f; ridx[a][b] = 0; }

  for (int nt = 0; nt < NTILES; ++nt) {
    const int n0 = ns0 + nt * BN;
    f32x4 acc[4][4];
#pragma unroll
    for (int a = 0; a < 4; ++a)
#pragma unroll
      for (int b = 0; b < 4; ++b) {
        f32x4 zz = {0.f, 0.f, 0.f, 0.f};
        acc[a][b] = zz;
      }

    for (int kc = 0; kc < DD; kc += BK) {
      __syncthreads();   // previous tile's LDS reads done
#pragma unroll
      for (int j = 0; j < 4; ++j) {
        const int grp = wid * 4 + j;               // 0..15
        const int o = grp * 512;                   // ushort offset = 1024B
        const int r = grp * 8 + st_r;              // 0..127
        const size_t ga = (size_t)(m0 + r) * DD + kc + st_g;
        const size_t gb = (size_t)(n0 + r) * DD + kc + st_g;
        gl2lds16(Ah + ga, Ahs + o);
        gl2lds16(Al + ga, Als + o);
        gl2lds16(Bh + gb, Bhs + o);
        gl2lds16(Bl + gb, Bls + o);
      }
      __syncthreads();   // staging complete (barrier drains vmcnt)
#pragma unroll
      for (int ks = 0; ks < BK; ks += 32) {
        const int ko = ks + lg * 8;
        bf16x8 ah[4], al[4], bh[4], bl[4];
#pragma unroll
        for (int mi = 0; mi < 4; ++mi) {
          const int r = wm * 64 + mi * 16 + l15;
          ah[mi] = *(const bf16x8*)&Ahs[r * BK + ko];
          al[mi] = *(const bf16x8*)&Als[r * BK + ko];
        }
#pragma unroll
        for (int ni = 0; ni < 4; ++ni) {
          const int r = wn * 64 + ni * 16 + l15;
          bh[ni] = *(const bf16x8*)&Bhs[r * BK + ko];
          bl[ni] = *(const bf16x8*)&Bls[r * BK + ko];
        }
#pragma unroll
        for (int mi = 0; mi < 4; ++mi)
#pragma unroll
          for (int ni = 0; ni < 4; ++ni) {
            acc[mi][ni] = __builtin_amdgcn_mfma_f32_16x16x32_bf16(ah[mi], bh[ni], acc[mi][ni], 0, 0, 0);
            acc[mi][ni] = __builtin_amdgcn_mfma_f32_16x16x32_bf16(ah[mi], bl[ni], acc[mi][ni], 0, 0, 0);
            acc[mi][ni] = __builtin_amdgcn_mfma_f32_16x16x32_bf16(al[mi], bh[ni], acc[mi][ni], 0, 0, 0);
          }
      }
    }
    // epilogue: dist = (zn + cn) - 2*dot, np op order
#pragma unroll
    for (int ni = 0; ni < 4; ++ni) {
      const int col = n0 + wn * 64 + ni * 16 + l15;
      const float cn = cnorm[col];
#pragma unroll
      for (int mi = 0; mi < 4; ++mi)
#pragma unroll
        for (int i = 0; i < 4; ++i) {
          const float s = __fadd_rn(zrow[mi][i], cn);
          const float v = __fsub_rn(s, __fmul_rn(2.0f, acc[mi][ni][i]));
          if (v < rmin[mi][i]) { rmin[mi][i] = v; ridx[mi][i] = col; }  // strict <: first idx wins
        }
    }
  }
  // 16-lane butterfly reduce (C/D: col=lane&15, row=(lane>>4)*4+i)
#pragma unroll
  for (int mi = 0; mi < 4; ++mi)
#pragma unroll
    for (int i = 0; i < 4; ++i) {
      float v = rmin[mi][i];
      int ix = ridx[mi][i];
#pragma unroll
      for (int d = 1; d < 16; d <<= 1) {
        float ov = __shfl_xor(v, d);
        int oi = __shfl_xor(ix, d);
        if (ov < v || (ov == v && oi < ix)) { v = ov; ix = oi; }
      }
      if (l15 == 0) {
        const int row = m0 + wm * 64 + mi * 16 + lg * 4 + i;
        const int part = spl * 2 + wn;   // RACE FIX: per-(split, wn) slot
        pval[(size_t)part * NQ + row] = v;
        pidx[(size_t)part * NQ + row] = ix;
      }
    }
}

// ---------- K3: combine partials, gather quantized, loss partial ----------
__global__ __launch_bounds__(256) void finalize_kernel(
    const float* __restrict__ pval, const int* __restrict__ pidx,
    const float* __restrict__ qc, const float* __restrict__ z,
    float* __restrict__ out, float* __restrict__ loss_acc) {
  __shared__ int sidx[8];
  __shared__ float red[256];
  const int bid = blockIdx.x;   // 2048 blocks * 8 rows
  const int t = threadIdx.x;
  if (t < 8) {
    const int row = bid * 8 + t;
    float best = pval[row];
    int bi = pidx[row];
    for (int s2 = 1; s2 < NPART; ++s2) {
      float v = pval[(size_t)s2 * NQ + row];
      int ix = pidx[(size_t)s2 * NQ + row];
      if (v < best || (v == best && ix < bi)) { best = v; bi = ix; }
    }
    sidx[t] = bi;
    out[4194305 + row] = (float)bi;   // encoding_indices as f32
  }
  __syncthreads();
  float d2 = 0.f;
#pragma unroll
  for (int r = 0; r < 8; ++r) {
    const int row = bid * 8 + r;
    const int ix = sidx[r];
    const float q = qc[(size_t)ix * 256 + t];
    const float zz = z[(size_t)row * 256 + t];
    out[(size_t)row * 256 + t] = q;   // STE output == quantized value-wise
    const float d = q - zz;
    d2 += d * d;
  }
  red[t] = d2;
  for (int st = 128; st; st >>= 1) {
    __syncthreads();
    if (t < st) red[t] += red[t + st];
  }
  if (t == 0) atomicAdd(loss_acc, red[0]);
}

// ---------- K4: scalar loss write ----------
__global__ void write_loss_kernel(const float* __restrict__ loss_acc, float* __restrict__ out) {
  // commitment_loss == codebook_loss numerically -> vq_loss = 1.25 * mean
  out[4194304] = 1.25f * loss_acc[0] / 4194304.0f;
}

// ---------- launch ----------
extern "C" void kernel_launch(void* const* d_in, const int* in_sizes, int n_in,
                              void* d_out, int out_size, void* d_ws, size_t ws_size,
                              hipStream_t stream) {
  const float* z = (const float*)d_in[0];
  const float* cb = (const float*)d_in[1];
  const float* W = (const float*)d_in[2];
  const float* bias = (const float*)d_in[3];
  float* out = (float*)d_out;
  char* ws = (char*)d_ws;

  constexpr size_t OFF_QC = 0;                      // 16 MB fp32 quant_codebook
  constexpr size_t OFF_AH = OFF_QC + 16777216;      // 8 MB each
  constexpr size_t OFF_AL = OFF_AH + 8388608;
  constexpr size_t OFF_BH = OFF_AL + 8388608;
  constexpr size_t OFF_BL = OFF_BH + 8388608;
  constexpr size_t OFF_CN = OFF_BL + 8388608;       // 64 KB code norms
  constexpr size_t OFF_ZN = OFF_CN + 65536;         // 64 KB query norms
  constexpr size_t OFF_PV = OFF_ZN + 65536;         // 1 MB partial vals (16 sets)
  constexpr size_t OFF_PI = OFF_PV + 1048576;       // 1 MB partial idx
  constexpr size_t OFF_ACC = OFF_PI + 1048576;      // 4 B loss accumulator

  float* qc = (float*)(ws + OFF_QC);
  u16* Ah = (u16*)(ws + OFF_AH);
  u16* Al = (u16*)(ws + OFF_AL);
  u16* Bh = (u16*)(ws + OFF_BH);
  u16* Bl = (u16*)(ws + OFF_BL);
  float* cn = (float*)(ws + OFF_CN);
  float* zn = (float*)(ws + OFF_ZN);
  float* pv = (float*)(ws + OFF_PV);
  int* pi = (int*)(ws + OFF_PI);
  float* lacc = (float*)(ws + OFF_ACC);

  hipMemsetAsync(lacc, 0, 4, stream);
  split_z_kernel<<<4096, 256, 0, stream>>>(z, Ah, Al);
  qc_gemm_kernel<<<1024, 256, 0, stream>>>(cb, W, bias, qc);
  norm256_kernel<<<NQ / 64, 64, 0, stream>>>(z, zn);
  norm256_kernel<<<NC / 64, 64, 0, stream>>>(qc, cn);
  split_qc_kernel<<<4096, 256, 0, stream>>>(qc, Bh, Bl);
  vq_argmin_kernel<<<(NQ / BM) * NSPLIT, 256, 0, stream>>>(Ah, Al, Bh, Bl, cn, zn, pv, pi);
  finalize_kernel<<<NQ / 8, 256, 0, stream>>>(pv, pi, qc, z, out, lacc);
  write_loss_kernel<<<1, 1, 0, stream>>>(lacc, out);
}

// Round 3
// 549.855 us; speedup vs baseline: 1.0586x; 1.0586x over previous
//
#include <hip/hip_runtime.h>

typedef unsigned short u16;
typedef __bf16 bf16x8 __attribute__((ext_vector_type(8)));
typedef float f32x4 __attribute__((ext_vector_type(4)));

#define NQ 16384       // queries (8*2048)
#define NC 16384       // codes
#define DD 256         // embed dim
#define BM 128
#define BN 128
#define BK 64
#define NSPLIT 8
#define NPART (NSPLIT * 2)            // 16: per-(split, wn) partials
#define NTILES ((NC / NSPLIT) / BN)   // 16

// ---------- fp32 -> bf16 hi/lo split (RNE) ----------
__device__ __forceinline__ u16 f2bf(float x) {
  unsigned u = __float_as_uint(x);
  u += 0x7fffu + ((u >> 16) & 1u);
  return (u16)(u >> 16);
}
__device__ __forceinline__ float bf2f(u16 h) {
  return __uint_as_float(((unsigned)h) << 16);
}

// async global->LDS, 16B per lane; LDS dest is wave-uniform base + lane*16
__device__ __forceinline__ void gl2lds16(const void* g, void* l) {
  __builtin_amdgcn_global_load_lds((__attribute__((address_space(1))) void*)g,
                                   (__attribute__((address_space(3))) void*)l,
                                   16, 0, 0);
}

// ---------- K0: split z into bf16 hi/lo ----------
__global__ __launch_bounds__(256) void split_z_kernel(const float* __restrict__ z,
                                                      u16* __restrict__ Ah,
                                                      u16* __restrict__ Al) {
  size_t i = (size_t)blockIdx.x * 256 + threadIdx.x;   // float4 index
  float4 v = ((const float4*)z)[i];
  float f[4] = {v.x, v.y, v.z, v.w};
  u16 hh[4], ll[4];
#pragma unroll
  for (int j = 0; j < 4; ++j) {
    hh[j] = f2bf(f[j]);
    ll[j] = f2bf(f[j] - bf2f(hh[j]));
  }
  ushort4 h; h.x = hh[0]; h.y = hh[1]; h.z = hh[2]; h.w = hh[3];
  ushort4 l; l.x = ll[0]; l.y = ll[1]; l.z = ll[2]; l.w = ll[3];
  ((ushort4*)Ah)[i] = h;
  ((ushort4*)Al)[i] = l;
}

// ---------- K0b: row norms in EXACT numpy pairwise order ----------
// np.sum(x*x) len-256: two 128-halves; each half: 8 accumulators
// r[j] = sum_{i step 8} x[i+j]^2, combined ((r0+r1)+(r2+r3))+((r4+r5)+(r6+r7));
// total = half0 + half1. Here j -> lane (8 lanes per row, coalesced 32B loads),
// tree combine via shfl_xor in the identical order. Bitwise == old kernel.
__global__ __launch_bounds__(256) void norm256_kernel(const float* __restrict__ x,
                                                      float* __restrict__ nrm) {
  const int t = threadIdx.x;
  const int j = t & 7;                    // accumulator index within row
  const int row = blockIdx.x * 32 + (t >> 3);
  const float* q = x + (size_t)row * 256;
  float half[2];
#pragma unroll
  for (int h = 0; h < 2; ++h) {
    const float* p = q + h * 128;
    float v0 = p[j];
    float r = __fmul_rn(v0, v0);
#pragma unroll
    for (int i = 8; i < 128; i += 8) {
      float v = p[i + j];
      r = __fadd_rn(r, __fmul_rn(v, v));
    }
    float s1 = __fadd_rn(r, __shfl_xor(r, 1));    // r0+r1 | r2+r3 | ...
    float s2 = __fadd_rn(s1, __shfl_xor(s1, 2));  // (r0+r1)+(r2+r3) | ...
    half[h] = __fadd_rn(s2, __shfl_xor(s2, 4));   // full 8-way, np tree order
  }
  if (j == 0) nrm[row] = __fadd_rn(half[0], half[1]);
}

// ---------- K1: qc = cb @ W^T + bias  (fp32, 64x64 tiles) ----------
// DO NOT change numerics here: dist rounding grid depends on qc bits, and this
// exact configuration produced zero index flips vs the np reference.
__global__ __launch_bounds__(256) void qc_gemm_kernel(const float* __restrict__ cb,
                                                      const float* __restrict__ W,
                                                      const float* __restrict__ bias,
                                                      float* __restrict__ qc) {
  __shared__ float As[64][33];
  __shared__ float Bs[64][33];
  const int bm = blockIdx.x >> 2;   // 256 row tiles
  const int bn = blockIdx.x & 3;    // 4 col tiles
  const int m0 = bm * 64, n0 = bn * 64;
  const int t = threadIdx.x;
  const int tx = t & 15, ty = t >> 4;
  float acc[4][4] = {};
  for (int kc = 0; kc < 256; kc += 32) {
    __syncthreads();
#pragma unroll
    for (int j = 0; j < 8; ++j) {
      int idx = j * 256 + t;            // 0..2047
      int r = idx >> 5, c = idx & 31;
      As[r][c] = cb[(size_t)(m0 + r) * 256 + kc + c];
      Bs[r][c] = W[(size_t)(n0 + r) * 256 + kc + c];
    }
    __syncthreads();
#pragma unroll
    for (int kk = 0; kk < 32; ++kk) {
      float a[4], b[4];
#pragma unroll
      for (int u = 0; u < 4; ++u) a[u] = As[ty * 4 + u][kk];
#pragma unroll
      for (int v = 0; v < 4; ++v) b[v] = Bs[tx * 4 + v][kk];
#pragma unroll
      for (int u = 0; u < 4; ++u)
#pragma unroll
        for (int v = 0; v < 4; ++v) acc[u][v] += a[u] * b[v];
    }
  }
#pragma unroll
  for (int u = 0; u < 4; ++u)
#pragma unroll
    for (int v = 0; v < 4; ++v) {
      int r = m0 + ty * 4 + u, c = n0 + tx * 4 + v;
      qc[(size_t)r * 256 + c] = acc[u][v] + bias[c];
    }
}

// ---------- K1b: per-row bf16 hi/lo split of qc ----------
__global__ __launch_bounds__(256) void split_qc_kernel(const float* __restrict__ qc,
                                                       u16* __restrict__ Bh,
                                                       u16* __restrict__ Bl) {
  size_t i = (size_t)blockIdx.x * 256 + threadIdx.x;   // float4 index
  float4 v = ((const float4*)qc)[i];
  float f[4] = {v.x, v.y, v.z, v.w};
  u16 hh[4], ll[4];
#pragma unroll
  for (int j = 0; j < 4; ++j) {
    hh[j] = f2bf(f[j]);
    ll[j] = f2bf(f[j] - bf2f(hh[j]));
  }
  ushort4 h; h.x = hh[0]; h.y = hh[1]; h.z = hh[2]; h.w = hh[3];
  ushort4 l; l.x = ll[0]; l.y = ll[1]; l.z = ll[2]; l.w = ll[3];
  ((ushort4*)Bh)[i] = h;
  ((ushort4*)Bl)[i] = l;
}

// ---------- K2: fused split-bf16 distance GEMM + argmin ----------
// LDS layout is XOR-swizzled: position p (16B chunk) of row r holds k-chunk
// p ^ (r&7). Staging achieves this by permuting the per-lane GLOBAL address
// (global_load_lds LDS dest is fixed contiguous); reads apply the same XOR.
// 16 consecutive rows then hit all 8 bank-groups (2-way = free) instead of
// one group 16-way. Fragment values (and thus all numerics) are unchanged.
__global__ __launch_bounds__(256, 2) void vq_argmin_kernel(
    const u16* __restrict__ Ah, const u16* __restrict__ Al,
    const u16* __restrict__ Bh, const u16* __restrict__ Bl,
    const float* __restrict__ cnorm, const float* __restrict__ znorm,
    float* __restrict__ pval, int* __restrict__ pidx) {
  __shared__ __align__(16) u16 Ahs[BM * BK];
  __shared__ __align__(16) u16 Als[BM * BK];
  __shared__ __align__(16) u16 Bhs[BN * BK];
  __shared__ __align__(16) u16 Bls[BN * BK];

  const int bm = blockIdx.x / NSPLIT;
  const int spl = blockIdx.x % NSPLIT;
  const int lane = threadIdx.x & 63;
  const int wid = threadIdx.x >> 6;
  const int wm = wid >> 1, wn = wid & 1;     // 2x2 wave grid, 64x64 each
  const int l15 = lane & 15;
  const int lg = lane >> 4;                  // 0..3
  const int m0 = bm * BM;
  const int ns0 = spl * (NC / NSPLIT);

  const int st_r = lane >> 3;                          // row within 8-row group
  const int st_g = (((lane & 7) ^ (lane >> 3)) << 3);  // SWIZZLED k elem offset

  // query-row norms for this lane's 16 C/D rows (row = wm*64+mi*16+lg*4+i)
  float zrow[4][4];
#pragma unroll
  for (int mi = 0; mi < 4; ++mi)
#pragma unroll
    for (int i = 0; i < 4; ++i)
      zrow[mi][i] = znorm[m0 + wm * 64 + mi * 16 + lg * 4 + i];

  float rmin[4][4];
  int ridx[4][4];
#pragma unroll
  for (int a = 0; a < 4; ++a)
#pragma unroll
    for (int b = 0; b < 4; ++b) { rmin[a][b] = 3.4e38f; ridx[a][b] = 0; }

  for (int nt = 0; nt < NTILES; ++nt) {
    const int n0 = ns0 + nt * BN;
    f32x4 acc[4][4];
#pragma unroll
    for (int a = 0; a < 4; ++a)
#pragma unroll
      for (int b = 0; b < 4; ++b) {
        f32x4 zz = {0.f, 0.f, 0.f, 0.f};
        acc[a][b] = zz;
      }

    for (int kc = 0; kc < DD; kc += BK) {
      __syncthreads();   // previous tile's LDS reads done
#pragma unroll
      for (int j = 0; j < 4; ++j) {
        const int grp = wid * 4 + j;               // 0..15
        const int o = grp * 512;                   // ushort offset = 1024B
        const int r = grp * 8 + st_r;              // 0..127
        const size_t ga = (size_t)(m0 + r) * DD + kc + st_g;
        const size_t gb = (size_t)(n0 + r) * DD + kc + st_g;
        gl2lds16(Ah + ga, Ahs + o);
        gl2lds16(Al + ga, Als + o);
        gl2lds16(Bh + gb, Bhs + o);
        gl2lds16(Bl + gb, Bls + o);
      }
      __syncthreads();   // staging complete (barrier drains vmcnt)
#pragma unroll
      for (int ks = 0; ks < BK; ks += 32) {
        const int c = (ks >> 3) + lg;              // k-chunk index 0..7
        bf16x8 ah[4], al[4], bh[4], bl[4];
#pragma unroll
        for (int mi = 0; mi < 4; ++mi) {
          const int r = wm * 64 + mi * 16 + l15;
          const int off = r * BK + ((c ^ (r & 7)) << 3);   // swizzled read
          ah[mi] = *(const bf16x8*)&Ahs[off];
          al[mi] = *(const bf16x8*)&Als[off];
        }
#pragma unroll
        for (int ni = 0; ni < 4; ++ni) {
          const int r = wn * 64 + ni * 16 + l15;
          const int off = r * BK + ((c ^ (r & 7)) << 3);   // swizzled read
          bh[ni] = *(const bf16x8*)&Bhs[off];
          bl[ni] = *(const bf16x8*)&Bls[off];
        }
#pragma unroll
        for (int mi = 0; mi < 4; ++mi)
#pragma unroll
          for (int ni = 0; ni < 4; ++ni) {
            acc[mi][ni] = __builtin_amdgcn_mfma_f32_16x16x32_bf16(ah[mi], bh[ni], acc[mi][ni], 0, 0, 0);
            acc[mi][ni] = __builtin_amdgcn_mfma_f32_16x16x32_bf16(ah[mi], bl[ni], acc[mi][ni], 0, 0, 0);
            acc[mi][ni] = __builtin_amdgcn_mfma_f32_16x16x32_bf16(al[mi], bh[ni], acc[mi][ni], 0, 0, 0);
          }
      }
    }
    // epilogue: dist = (zn + cn) - 2*dot, np op order
#pragma unroll
    for (int ni = 0; ni < 4; ++ni) {
      const int col = n0 + wn * 64 + ni * 16 + l15;
      const float cn = cnorm[col];
#pragma unroll
      for (int mi = 0; mi < 4; ++mi)
#pragma unroll
        for (int i = 0; i < 4; ++i) {
          const float s = __fadd_rn(zrow[mi][i], cn);
          const float v = __fsub_rn(s, __fmul_rn(2.0f, acc[mi][ni][i]));
          if (v < rmin[mi][i]) { rmin[mi][i] = v; ridx[mi][i] = col; }  // strict <: first idx wins
        }
    }
  }
  // 16-lane butterfly reduce (C/D: col=lane&15, row=(lane>>4)*4+i)
#pragma unroll
  for (int mi = 0; mi < 4; ++mi)
#pragma unroll
    for (int i = 0; i < 4; ++i) {
      float v = rmin[mi][i];
      int ix = ridx[mi][i];
#pragma unroll
      for (int d = 1; d < 16; d <<= 1) {
        float ov = __shfl_xor(v, d);
        int oi = __shfl_xor(ix, d);
        if (ov < v || (ov == v && oi < ix)) { v = ov; ix = oi; }
      }
      if (l15 == 0) {
        const int row = m0 + wm * 64 + mi * 16 + lg * 4 + i;
        const int part = spl * 2 + wn;   // per-(split, wn) slot
        pval[(size_t)part * NQ + row] = v;
        pidx[(size_t)part * NQ + row] = ix;
      }
    }
}

// ---------- K3: combine partials, gather quantized, loss partial ----------
__global__ __launch_bounds__(256) void finalize_kernel(
    const float* __restrict__ pval, const int* __restrict__ pidx,
    const float* __restrict__ qc, const float* __restrict__ z,
    float* __restrict__ out, float* __restrict__ loss_acc) {
  __shared__ int sidx[8];
  __shared__ float red[256];
  const int bid = blockIdx.x;   // 2048 blocks * 8 rows
  const int t = threadIdx.x;
  if (t < 8) {
    const int row = bid * 8 + t;
    float best = pval[row];
    int bi = pidx[row];
    for (int s2 = 1; s2 < NPART; ++s2) {
      float v = pval[(size_t)s2 * NQ + row];
      int ix = pidx[(size_t)s2 * NQ + row];
      if (v < best || (v == best && ix < bi)) { best = v; bi = ix; }
    }
    sidx[t] = bi;
    out[4194305 + row] = (float)bi;   // encoding_indices as f32
  }
  __syncthreads();
  float d2 = 0.f;
#pragma unroll
  for (int r = 0; r < 8; ++r) {
    const int row = bid * 8 + r;
    const int ix = sidx[r];
    const float q = qc[(size_t)ix * 256 + t];
    const float zz = z[(size_t)row * 256 + t];
    out[(size_t)row * 256 + t] = q;   // STE output == quantized value-wise
    const float d = q - zz;
    d2 += d * d;
  }
  red[t] = d2;
  for (int st = 128; st; st >>= 1) {
    __syncthreads();
    if (t < st) red[t] += red[t + st];
  }
  if (t == 0) atomicAdd(loss_acc, red[0]);
}

// ---------- K4: scalar loss write ----------
__global__ void write_loss_kernel(const float* __restrict__ loss_acc, float* __restrict__ out) {
  // commitment_loss == codebook_loss numerically -> vq_loss = 1.25 * mean
  out[4194304] = 1.25f * loss_acc[0] / 4194304.0f;
}

// ---------- launch ----------
extern "C" void kernel_launch(void* const* d_in, const int* in_sizes, int n_in,
                              void* d_out, int out_size, void* d_ws, size_t ws_size,
                              hipStream_t stream) {
  const float* z = (const float*)d_in[0];
  const float* cb = (const float*)d_in[1];
  const float* W = (const float*)d_in[2];
  const float* bias = (const float*)d_in[3];
  float* out = (float*)d_out;
  char* ws = (char*)d_ws;

  constexpr size_t OFF_QC = 0;                      // 16 MB fp32 quant_codebook
  constexpr size_t OFF_AH = OFF_QC + 16777216;      // 8 MB each
  constexpr size_t OFF_AL = OFF_AH + 8388608;
  constexpr size_t OFF_BH = OFF_AL + 8388608;
  constexpr size_t OFF_BL = OFF_BH + 8388608;
  constexpr size_t OFF_CN = OFF_BL + 8388608;       // 64 KB code norms
  constexpr size_t OFF_ZN = OFF_CN + 65536;         // 64 KB query norms
  constexpr size_t OFF_PV = OFF_ZN + 65536;         // 1 MB partial vals (16 sets)
  constexpr size_t OFF_PI = OFF_PV + 1048576;       // 1 MB partial idx
  constexpr size_t OFF_ACC = OFF_PI + 1048576;      // 4 B loss accumulator

  float* qc = (float*)(ws + OFF_QC);
  u16* Ah = (u16*)(ws + OFF_AH);
  u16* Al = (u16*)(ws + OFF_AL);
  u16* Bh = (u16*)(ws + OFF_BH);
  u16* Bl = (u16*)(ws + OFF_BL);
  float* cn = (float*)(ws + OFF_CN);
  float* zn = (float*)(ws + OFF_ZN);
  float* pv = (float*)(ws + OFF_PV);
  int* pi = (int*)(ws + OFF_PI);
  float* lacc = (float*)(ws + OFF_ACC);

  hipMemsetAsync(lacc, 0, 4, stream);
  split_z_kernel<<<4096, 256, 0, stream>>>(z, Ah, Al);
  qc_gemm_kernel<<<1024, 256, 0, stream>>>(cb, W, bias, qc);
  norm256_kernel<<<NQ / 32, 256, 0, stream>>>(z, zn);
  norm256_kernel<<<NC / 32, 256, 0, stream>>>(qc, cn);
  split_qc_kernel<<<4096, 256, 0, stream>>>(qc, Bh, Bl);
  vq_argmin_kernel<<<(NQ / BM) * NSPLIT, 256, 0, stream>>>(Ah, Al, Bh, Bl, cn, zn, pv, pi);
  finalize_kernel<<<NQ / 8, 256, 0, stream>>>(pv, pi, qc, z, out, lacc);
  write_loss_kernel<<<1, 1, 0, stream>>>(lacc, out);
}